// Round 8
// baseline (810.953 us; speedup 1.0000x reference)
//
#include <hip/hip_runtime.h>
#include <math.h>

#define NR 4096
#define DD 512
#define MM 50000
#define CAP 640
#define TK 64
#define T0 0.105f
#define QS 400.0f
#define QINV (1.0f / 160000.0f)

typedef unsigned int u32;
typedef unsigned short u16;
typedef int i32x4 __attribute__((ext_vector_type(4)));

#define AS1 __attribute__((address_space(1)))
#define AS3 __attribute__((address_space(3)))

__device__ __forceinline__ u16 f2bf(float f) {
    u32 u = __float_as_uint(f);
    u32 r = (u + 0x7FFFu + ((u >> 16) & 1u)) >> 16;   // RNE
    return (u16)r;
}

// ---------------- ws layout ----------------
// [0,16384)                cnt (4096 u32)  -- zeroed each launch
// [16384,17408)            geom partials (256 f32, fully written)
// [32768,32772)            e_geom scalar
// [65536, +2MB)            xi8  (4096x512 int8, scale 400)
// [+2MB, +27.6MB)          mui8 (50000x512 int8)
// [+27.6MB, +38.1MB)       cand keys (4096 x 640 u32 = {bf16val:16, idx:16})

// ============ int8 symmetric quantization (RNE, scale 400) ============
__global__ __launch_bounds__(256) void k_quant(const float* __restrict__ src,
                                               char* __restrict__ dst, int n8) {
    int i = blockIdx.x * 256 + threadIdx.x;
    if (i >= n8) return;
    const float4* s4 = (const float4*)src;
    float4 a = s4[(size_t)i * 2], b = s4[(size_t)i * 2 + 1];
    float v[8] = {a.x, a.y, a.z, a.w, b.x, b.y, b.z, b.w};
    u32 lo = 0, hi = 0;
#pragma unroll
    for (int j = 0; j < 4; ++j) {
        int q = __float2int_rn(v[j] * QS);
        q = q > 127 ? 127 : (q < -127 ? -127 : q);
        lo |= ((u32)(unsigned char)(char)q) << (8 * j);
    }
#pragma unroll
    for (int j = 0; j < 4; ++j) {
        int q = __float2int_rn(v[4 + j] * QS);
        q = q > 127 ? 127 : (q < -127 ? -127 : q);
        hi |= ((u32)(unsigned char)(char)q) << (8 * j);
    }
    *(uint2*)(dst + (size_t)i * 8) = make_uint2(lo, hi);
}

// ============ i8 MFMA GEMM x @ mu^T, 256x256 tile, threshold push ============
// BK=128 (128-B LDS rows, proven conflict-free swizzle), 8 waves (2M x 4N,
// 128x64 out each), dbuf 128 KB. ONE barrier + ONE aged vmcnt(0) per K-tile:
// tile t's loads are waited a full compute-phase after issue -> zero exposure.
__global__ __launch_bounds__(512, 2) void k_gemm_topk(
    const char* __restrict__ xi8, const char* __restrict__ mui8,
    u32* __restrict__ cnt, u32* __restrict__ cand)
{
    __shared__ char smem[131072];         // 2 x (A 32KB + B 32KB)

    const int t = threadIdx.x;
    const int lane = t & 63;
    const int wid = t >> 6;               // 0..7
    const int wr = wid >> 2, wc = wid & 3;
    const int fr = lane & 15, fq = lane >> 4;
    const int r0 = blockIdx.x * 256;      // x row panel (fastest)
    const int c0 = blockIdx.y * 256;      // mu col panel

    i32x4 acc[8][4];
#pragma unroll
    for (int m = 0; m < 8; ++m)
#pragma unroll
        for (int n = 0; n < 4; ++n) acc[m][n] = (i32x4){0, 0, 0, 0};

    auto STAGE = [&](int cur, int kt) {
        char* Ab = smem + cur * 65536;
        char* Bb = Ab + 32768;
#pragma unroll
        for (int i = 0; i < 4; ++i) {
            const int L  = i * 8192 + t * 16;
            const int rw = L >> 7;                 // 0..255 (128-B rows)
            const int cb = (L & 127) ^ ((rw & 7) << 4);
            const char* srcA = xi8 + (size_t)(r0 + rw) * DD + kt + cb;
            __builtin_amdgcn_global_load_lds((const AS1 u32*)srcA, (AS3 u32*)(Ab + L), 16, 0, 0);
            int gr = c0 + rw; if (gr > MM - 1) gr = MM - 1;   // clamp, filtered at push
            const char* srcB = mui8 + (size_t)gr * DD + kt + cb;
            __builtin_amdgcn_global_load_lds((const AS1 u32*)srcB, (AS3 u32*)(Bb + L), 16, 0, 0);
        }
    };

    auto COMPUTE = [&](int cur) {
        const char* Ab = (const char*)smem + cur * 65536;
        const char* Bb = Ab + 32768;
#pragma unroll
        for (int kk = 0; kk < 2; ++kk) {          // two K=64 halves of BK=128
            i32x4 af[8], bfr[4];
#pragma unroll
            for (int m = 0; m < 8; ++m) {
                const int ra = wr * 128 + m * 16 + fr;
                af[m] = *(const i32x4*)(Ab + ((ra << 7) | ((kk * 64 + fq * 16) ^ ((ra & 7) << 4))));
            }
#pragma unroll
            for (int n = 0; n < 4; ++n) {
                const int rb = wc * 64 + n * 16 + fr;
                bfr[n] = *(const i32x4*)(Bb + ((rb << 7) | ((kk * 64 + fq * 16) ^ ((rb & 7) << 4))));
            }
#pragma unroll
            for (int m = 0; m < 8; ++m)
#pragma unroll
                for (int n = 0; n < 4; ++n)
                    acc[m][n] = __builtin_amdgcn_mfma_i32_16x16x64_i8(af[m], bfr[n], acc[m][n], 0, 0, 0);
        }
    };

    STAGE(0, 0);
#pragma unroll
    for (int ts = 0; ts < 4; ++ts) {              // 512/128 = 4 K-tiles
        const int cur = ts & 1;
        asm volatile("s_waitcnt vmcnt(0)" ::: "memory");  // tile ts resident (aged 1 phase)
        __builtin_amdgcn_s_barrier();             // visible to all + prev readers done
        __builtin_amdgcn_sched_barrier(0);
        if (ts < 3) STAGE(cur ^ 1, (ts + 1) * 128);   // flies under the whole compute
        __builtin_amdgcn_sched_barrier(0);
        __builtin_amdgcn_s_setprio(1);
        COMPUTE(cur);
        __builtin_amdgcn_s_setprio(0);
        __builtin_amdgcn_sched_barrier(0);
    }

    // C/D layout (m89): col = lane&15, row = (lane>>4)*4 + reg
#pragma unroll
    for (int m = 0; m < 8; ++m) {
        const int rowb = r0 + wr * 128 + m * 16 + fq * 4;
#pragma unroll
        for (int n = 0; n < 4; ++n) {
            const int col = c0 + wc * 64 + n * 16 + fr;
#pragma unroll
            for (int r = 0; r < 4; ++r) {
                const float v = (float)acc[m][n][r] * QINV;
                if (v >= T0 && col < MM) {
                    u32 pos = atomicAdd(&cnt[rowb + r], 1u);
                    if (pos < CAP)
                        cand[(size_t)(rowb + r) * CAP + pos] =
                            (((u32)f2bf(v)) << 16) | (u32)col;
                }
            }
        }
    }
}

// ============ x @ x^T geometric energy (same 256^2 structure, triangular) ====
__global__ __launch_bounds__(512, 2) void k_geom(
    const char* __restrict__ xi8, float* __restrict__ partial)
{
    const int bx = blockIdx.x, by = blockIdx.y;
    const int t = threadIdx.x;
    if (bx < by) { if (t == 0) partial[by * 16 + bx] = 0.f; return; }

    __shared__ char smem[131072];
    __shared__ float red[8];

    const int lane = t & 63;
    const int wid = t >> 6;
    const int wr = wid >> 2, wc = wid & 3;
    const int fr = lane & 15, fq = lane >> 4;
    const int r0 = by * 256;
    const int c0 = bx * 256;

    i32x4 acc[8][4];
#pragma unroll
    for (int m = 0; m < 8; ++m)
#pragma unroll
        for (int n = 0; n < 4; ++n) acc[m][n] = (i32x4){0, 0, 0, 0};

    auto STAGE = [&](int cur, int kt) {
        char* Ab = smem + cur * 65536;
        char* Bb = Ab + 32768;
#pragma unroll
        for (int i = 0; i < 4; ++i) {
            const int L  = i * 8192 + t * 16;
            const int rw = L >> 7;
            const int cb = (L & 127) ^ ((rw & 7) << 4);
            const char* srcA = xi8 + (size_t)(r0 + rw) * DD + kt + cb;
            __builtin_amdgcn_global_load_lds((const AS1 u32*)srcA, (AS3 u32*)(Ab + L), 16, 0, 0);
            const char* srcB = xi8 + (size_t)(c0 + rw) * DD + kt + cb;
            __builtin_amdgcn_global_load_lds((const AS1 u32*)srcB, (AS3 u32*)(Bb + L), 16, 0, 0);
        }
    };

    auto COMPUTE = [&](int cur) {
        const char* Ab = (const char*)smem + cur * 65536;
        const char* Bb = Ab + 32768;
#pragma unroll
        for (int kk = 0; kk < 2; ++kk) {
            i32x4 af[8], bfr[4];
#pragma unroll
            for (int m = 0; m < 8; ++m) {
                const int ra = wr * 128 + m * 16 + fr;
                af[m] = *(const i32x4*)(Ab + ((ra << 7) | ((kk * 64 + fq * 16) ^ ((ra & 7) << 4))));
            }
#pragma unroll
            for (int n = 0; n < 4; ++n) {
                const int rb = wc * 64 + n * 16 + fr;
                bfr[n] = *(const i32x4*)(Bb + ((rb << 7) | ((kk * 64 + fq * 16) ^ ((rb & 7) << 4))));
            }
#pragma unroll
            for (int m = 0; m < 8; ++m)
#pragma unroll
                for (int n = 0; n < 4; ++n)
                    acc[m][n] = __builtin_amdgcn_mfma_i32_16x16x64_i8(af[m], bfr[n], acc[m][n], 0, 0, 0);
        }
    };

    STAGE(0, 0);
#pragma unroll
    for (int ts = 0; ts < 4; ++ts) {
        const int cur = ts & 1;
        asm volatile("s_waitcnt vmcnt(0)" ::: "memory");
        __builtin_amdgcn_s_barrier();
        __builtin_amdgcn_sched_barrier(0);
        if (ts < 3) STAGE(cur ^ 1, (ts + 1) * 128);
        __builtin_amdgcn_sched_barrier(0);
        __builtin_amdgcn_s_setprio(1);
        COMPUTE(cur);
        __builtin_amdgcn_s_setprio(0);
        __builtin_amdgcn_sched_barrier(0);
    }

    float local = 0.f;
#pragma unroll
    for (int m = 0; m < 8; ++m) {
        const int rowb = r0 + wr * 128 + m * 16 + fq * 4;
#pragma unroll
        for (int n = 0; n < 4; ++n) {
            const int col = c0 + wc * 64 + n * 16 + fr;
#pragma unroll
            for (int r = 0; r < 4; ++r) {
                if (rowb + r != col) {
                    float s = fminf((float)acc[m][n][r] * QINV, 0.9999f);
                    local += -logf(1.0f - s + 1e-4f);
                }
            }
        }
    }
    if (bx > by) local *= 2.f;   // symmetric half counted twice

#pragma unroll
    for (int off = 32; off >= 1; off >>= 1) local += __shfl_xor(local, off, 64);
    if (lane == 0) red[wid] = local;
    __syncthreads();
    if (t == 0) {
        float s = 0.f;
        for (int i = 0; i < 8; ++i) s += red[i];
        partial[by * 16 + bx] = s;
    }
}

__global__ void k_reduce_geom(const float* __restrict__ partial, float* __restrict__ egeom)
{
    __shared__ float red[4];
    const int t = threadIdx.x;
    float v = partial[t];
#pragma unroll
    for (int off = 32; off >= 1; off >>= 1) v += __shfl_xor(v, off, 64);
    const int wave = t >> 6, lane = t & 63;
    if (lane == 0) red[wave] = v;
    __syncthreads();
    if (t == 0) {
        float s = red[0] + red[1] + red[2] + red[3];
        egeom[0] = s / ((float)NR * (float)(NR - 1));
    }
}

// ============ top-64 by key -> exact fp32 recompute -> top-32 -> epilogue ====
__global__ __launch_bounds__(256) void k_finalize(
    const u32* __restrict__ cand, const u32* __restrict__ cnt,
    const float* __restrict__ x, const float* __restrict__ mu,
    const float* __restrict__ alpha, const float* __restrict__ kappa,
    const float* __restrict__ Ww, const float* __restrict__ Wb,
    const float* __restrict__ egeom, float* __restrict__ out)
{
    __shared__ u32   keys[4][CAP];
    __shared__ int   selid[4][TK];
    __shared__ float selex[4][TK];

    const int t = threadIdx.x, wave = t >> 6, lane = t & 63;
    const int row = blockIdx.x * 4 + wave;
    const int cn = (int)cnt[row];
    const int c = cn < CAP ? cn : CAP;

    for (int s = lane; s < c; s += 64)
        keys[wave][s] = cand[(size_t)row * CAP + s];
    __syncthreads();

    // iterative argmax: top-TK keys (value-major; distinct idx => no ties)
    for (int k = 0; k < TK; ++k) {
        u32 best = 0u; int bpos = -1;
        for (int s = lane; s < c; s += 64) {
            u32 v = keys[wave][s];
            if (v > best) { best = v; bpos = s; }
        }
#pragma unroll
        for (int off = 32; off >= 1; off >>= 1) {
            u32 v2 = __shfl_xor(best, off, 64);
            int p2 = __shfl_xor(bpos, off, 64);
            if (v2 > best) { best = v2; bpos = p2; }
        }
        if (lane == 0) {
            selid[wave][k] = (bpos >= 0) ? (int)(best & 0xFFFFu) : -1;
            if (bpos >= 0) keys[wave][bpos] = 0u;
        }
        __syncthreads();
    }

    // exact fp32 dots for the TK selected candidates (batched 4-wide)
    float xr[8];
    {
        const float4* xp = (const float4*)(x + (size_t)row * DD);
        float4 a = xp[lane * 2], b = xp[lane * 2 + 1];
        xr[0] = a.x; xr[1] = a.y; xr[2] = a.z; xr[3] = a.w;
        xr[4] = b.x; xr[5] = b.y; xr[6] = b.z; xr[7] = b.w;
    }
    for (int s0 = 0; s0 < TK; s0 += 4) {
        int idv[4];
        float4 a0[4], a1[4];
#pragma unroll
        for (int j = 0; j < 4; ++j) {
            idv[j] = selid[wave][s0 + j];              // wave-uniform
            const int rid = idv[j] >= 0 ? idv[j] : 0;
            const float4* mp = (const float4*)(mu + (size_t)rid * DD);
            a0[j] = mp[lane * 2];
            a1[j] = mp[lane * 2 + 1];
        }
        float d[4];
#pragma unroll
        for (int j = 0; j < 4; ++j)
            d[j] = xr[0] * a0[j].x + xr[1] * a0[j].y + xr[2] * a0[j].z + xr[3] * a0[j].w
                 + xr[4] * a1[j].x + xr[5] * a1[j].y + xr[6] * a1[j].z + xr[7] * a1[j].w;
#pragma unroll
        for (int j = 0; j < 4; ++j) {
#pragma unroll
            for (int off = 32; off >= 1; off >>= 1) d[j] += __shfl_xor(d[j], off, 64);
            if (lane == 0) selex[wave][s0 + j] = (idv[j] >= 0) ? d[j] : -INFINITY;
        }
    }
    __syncthreads();

    float v = selex[wave][lane];
    const int id = selid[wave][lane];
    bool alive = (id >= 0);

    // drop the 32 smallest exact values -> exact top-32 remains
    for (int rdrop = 0; rdrop < 32; ++rdrop) {
        float mn = alive ? v : INFINITY;
        int  mp2 = alive ? lane : 64;
#pragma unroll
        for (int off = 32; off >= 1; off >>= 1) {
            float m2 = __shfl_xor(mn, off, 64);
            int   p2 = __shfl_xor(mp2, off, 64);
            if (m2 < mn || (m2 == mn && p2 < mp2)) { mn = m2; mp2 = p2; }
        }
        if (lane == mp2) alive = false;
    }

    const float dv = alive ? v : -INFINITY;

    // top-1 / top-2 exact values (u, v of the reference)
    float m1 = dv; int p1 = alive ? lane : 64;
#pragma unroll
    for (int off = 32; off >= 1; off >>= 1) {
        float m2 = __shfl_xor(m1, off, 64);
        int   p2 = __shfl_xor(p1, off, 64);
        if (m2 > m1 || (m2 == m1 && p2 < p1)) { m1 = m2; p1 = p2; }
    }
    const float uu = m1;
    float s1 = (lane == p1) ? -INFINITY : dv;
#pragma unroll
    for (int off = 32; off >= 1; off >>= 1) s1 = fmaxf(s1, __shfl_xor(s1, off, 64));
    const float vv = s1;

    const int gid = alive ? id : 0;
    const float av = alpha[gid];
    const float kv = kappa[gid];
    float imp = alive ? fmaxf(kv, 1e-4f) : 0.f;
    float simp = imp;
#pragma unroll
    for (int off = 32; off >= 1; off >>= 1) simp += __shfl_xor(simp, off, 64);
    float w = fmaxf(imp / simp, 1e-8f);
    float tk = alive ? (av * (dv - 1.0f) * 10.0f + logf(w)) : -INFINITY;
    float mx = tk;
#pragma unroll
    for (int off = 32; off >= 1; off >>= 1) mx = fmaxf(mx, __shfl_xor(mx, off, 64));
    float se = alive ? expf(tk - mx) : 0.f;
#pragma unroll
    for (int off = 32; off >= 1; off >>= 1) se += __shfl_xor(se, off, 64);

    if (lane == 0) {
        float esplat = -(mx + logf(se));
        float z = Ww[0] * uu + Ww[1] * vv + Ww[2] * uu * vv + Wb[0];
        float ecomp = 1.f / (1.f + expf(-z));
        out[row] = esplat + 0.1f * egeom[0] + 0.1f * ecomp;
    }
}

extern "C" void kernel_launch(void* const* d_in, const int* in_sizes, int n_in,
                              void* d_out, int out_size, void* d_ws, size_t ws_size,
                              hipStream_t stream)
{
    const float* x     = (const float*)d_in[0];
    const float* mu    = (const float*)d_in[1];
    const float* alpha = (const float*)d_in[2];
    const float* kappa = (const float*)d_in[3];
    const float* Ww    = (const float*)d_in[4];
    const float* Wb    = (const float*)d_in[5];
    float* out = (float*)d_out;

    char* ws = (char*)d_ws;
    u32*   cnt     = (u32*)ws;
    float* partial = (float*)(ws + 16384);
    float* egeom   = (float*)(ws + 32768);
    char*  xi8     = (char*)(ws + 65536);
    char*  mui8    = (char*)(ws + 65536 + 2097152);
    u32*   cand    = (u32*)(ws + 65536 + 2097152 + 25600000);

    hipMemsetAsync(cnt, 0, NR * sizeof(u32), stream);

    k_quant<<<(NR * DD / 8 + 255) / 256, 256, 0, stream>>>(x, xi8, NR * DD / 8);
    k_quant<<<(MM * DD / 8 + 255) / 256, 256, 0, stream>>>(mu, mui8, MM * DD / 8);

    dim3 g1(NR / 256, (MM + 255) / 256);   // 16 x 196, row-panel fastest
    k_gemm_topk<<<g1, 512, 0, stream>>>(xi8, mui8, cnt, cand);

    dim3 g2(16, 16);
    k_geom<<<g2, 512, 0, stream>>>(xi8, partial);

    k_reduce_geom<<<1, 256, 0, stream>>>(partial, egeom);

    k_finalize<<<NR / 4, 256, 0, stream>>>(cand, cnt, x, mu, alpha, kappa, Ww, Wb, egeom, out);
}

// Round 9
// 602.558 us; speedup vs baseline: 1.3458x; 1.3458x over previous
//
#include <hip/hip_runtime.h>
#include <math.h>

#define NR 4096
#define DD 512
#define MM 50000
#define CAP 640
#define TK 64
#define T0 0.105f
#define QS 400.0f
#define QINV (1.0f / 160000.0f)

typedef unsigned int u32;
typedef unsigned short u16;
typedef int i32x4 __attribute__((ext_vector_type(4)));

#define AS1 __attribute__((address_space(1)))
#define AS3 __attribute__((address_space(3)))

__device__ __forceinline__ u16 f2bf(float f) {
    u32 u = __float_as_uint(f);
    u32 r = (u + 0x7FFFu + ((u >> 16) & 1u)) >> 16;   // RNE
    return (u16)r;
}

// ---------------- ws layout ----------------
// [0,16384)                cnt (4096 u32)  -- zeroed each launch
// [16384,20480)            geom partials (1024 f32, fully written)
// [32768,32772)            e_geom scalar
// [65536, +2MB)            xi8  (4096x512 int8, scale 400)
// [+2MB, +27.6MB)          mui8 (50000x512 int8)
// [+27.6MB, +38.1MB)       cand keys (4096 x 640 u32 = {bf16val:16, idx:16})

// ============ int8 symmetric quantization (RNE, scale 400) ============
__global__ __launch_bounds__(256) void k_quant(const float* __restrict__ src,
                                               char* __restrict__ dst, int n8) {
    int i = blockIdx.x * 256 + threadIdx.x;
    if (i >= n8) return;
    const float4* s4 = (const float4*)src;
    float4 a = s4[(size_t)i * 2], b = s4[(size_t)i * 2 + 1];
    float v[8] = {a.x, a.y, a.z, a.w, b.x, b.y, b.z, b.w};
    u32 lo = 0, hi = 0;
#pragma unroll
    for (int j = 0; j < 4; ++j) {
        int q = __float2int_rn(v[j] * QS);
        q = q > 127 ? 127 : (q < -127 ? -127 : q);
        lo |= ((u32)(unsigned char)(char)q) << (8 * j);
    }
#pragma unroll
    for (int j = 0; j < 4; ++j) {
        int q = __float2int_rn(v[4 + j] * QS);
        q = q > 127 ? 127 : (q < -127 ? -127 : q);
        hi |= ((u32)(unsigned char)(char)q) << (8 * j);
    }
    *(uint2*)(dst + (size_t)i * 8) = make_uint2(lo, hi);
}

// ============ i8 MFMA GEMM x @ mu^T, 128x128 tile, threshold push ============
// BK=128 (128-B LDS rows, measured-zero-conflict swizzle, R6), SINGLE buffer
// 32 KB -> 5 blocks/CU. Latency hidden by 5 independent barrier groups per CU
// (TLP), not intra-block pipelining (null in R4/R7/R8).
__global__ __launch_bounds__(256, 5) void k_gemm_topk(
    const char* __restrict__ xi8, const char* __restrict__ mui8,
    u32* __restrict__ cnt, u32* __restrict__ cand)
{
    __shared__ char smem[32768];          // A 16KB | B 16KB

    const int t = threadIdx.x;
    const int lane = t & 63;
    const int wid = t >> 6;
    const int wr = wid >> 1, wc = wid & 1;
    const int fr = lane & 15, fq = lane >> 4;
    const int r0 = blockIdx.x * 128;      // x row panel (fastest)
    const int c0 = blockIdx.y * 128;      // mu col panel

    i32x4 acc[4][4];
#pragma unroll
    for (int m = 0; m < 4; ++m)
#pragma unroll
        for (int n = 0; n < 4; ++n) acc[m][n] = (i32x4){0, 0, 0, 0};

    for (int kt = 0; kt < DD; kt += 128) {
        __syncthreads();                  // previous tile fully consumed
#pragma unroll
        for (int i = 0; i < 4; ++i) {
            const int L  = i * 4096 + t * 16;
            const int rw = L >> 7;                 // 0..127 (128-B rows)
            const int cb = (L & 127) ^ ((rw & 7) << 4);
            const char* srcA = xi8 + (size_t)(r0 + rw) * DD + kt + cb;
            __builtin_amdgcn_global_load_lds((const AS1 u32*)srcA, (AS3 u32*)(smem + L), 16, 0, 0);
            int gr = c0 + rw; if (gr > MM - 1) gr = MM - 1;   // clamp, filtered at push
            const char* srcB = mui8 + (size_t)gr * DD + kt + cb;
            __builtin_amdgcn_global_load_lds((const AS1 u32*)srcB, (AS3 u32*)(smem + 16384 + L), 16, 0, 0);
        }
        __syncthreads();                  // staged tile visible (vmcnt drained)
#pragma unroll
        for (int kk = 0; kk < 2; ++kk) {  // two K=64 halves of BK=128
            i32x4 af[4], bfr[4];
#pragma unroll
            for (int m = 0; m < 4; ++m) {
                const int ra = wr * 64 + m * 16 + fr;
                af[m] = *(const i32x4*)(smem + ((ra << 7) | ((kk * 64 + fq * 16) ^ ((ra & 7) << 4))));
            }
#pragma unroll
            for (int n = 0; n < 4; ++n) {
                const int rb = wc * 64 + n * 16 + fr;
                bfr[n] = *(const i32x4*)(smem + 16384 + ((rb << 7) | ((kk * 64 + fq * 16) ^ ((rb & 7) << 4))));
            }
#pragma unroll
            for (int m = 0; m < 4; ++m)
#pragma unroll
                for (int n = 0; n < 4; ++n)
                    acc[m][n] = __builtin_amdgcn_mfma_i32_16x16x64_i8(af[m], bfr[n], acc[m][n], 0, 0, 0);
        }
    }

    // C/D layout (m89): col = lane&15, row = (lane>>4)*4 + reg
#pragma unroll
    for (int m = 0; m < 4; ++m) {
        const int rowb = r0 + wr * 64 + m * 16 + fq * 4;
#pragma unroll
        for (int n = 0; n < 4; ++n) {
            const int col = c0 + wc * 64 + n * 16 + fr;
#pragma unroll
            for (int r = 0; r < 4; ++r) {
                const float v = (float)acc[m][n][r] * QINV;
                if (v >= T0 && col < MM) {
                    u32 pos = atomicAdd(&cnt[rowb + r], 1u);
                    if (pos < CAP)
                        cand[(size_t)(rowb + r) * CAP + pos] =
                            (((u32)f2bf(v)) << 16) | (u32)col;
                }
            }
        }
    }
}

// ============ x @ x^T geometric energy (same structure, triangular) ========
__global__ __launch_bounds__(256, 5) void k_geom(
    const char* __restrict__ xi8, float* __restrict__ partial)
{
    const int bx = blockIdx.x, by = blockIdx.y;
    const int t = threadIdx.x;
    if (bx < by) { if (t == 0) partial[by * 32 + bx] = 0.f; return; }

    __shared__ char smem[32768];
    __shared__ float red[4];

    const int lane = t & 63;
    const int wid = t >> 6;
    const int wr = wid >> 1, wc = wid & 1;
    const int fr = lane & 15, fq = lane >> 4;
    const int r0 = by * 128;
    const int c0 = bx * 128;

    i32x4 acc[4][4];
#pragma unroll
    for (int m = 0; m < 4; ++m)
#pragma unroll
        for (int n = 0; n < 4; ++n) acc[m][n] = (i32x4){0, 0, 0, 0};

    for (int kt = 0; kt < DD; kt += 128) {
        __syncthreads();
#pragma unroll
        for (int i = 0; i < 4; ++i) {
            const int L  = i * 4096 + t * 16;
            const int rw = L >> 7;
            const int cb = (L & 127) ^ ((rw & 7) << 4);
            const char* srcA = xi8 + (size_t)(r0 + rw) * DD + kt + cb;
            __builtin_amdgcn_global_load_lds((const AS1 u32*)srcA, (AS3 u32*)(smem + L), 16, 0, 0);
            const char* srcB = xi8 + (size_t)(c0 + rw) * DD + kt + cb;
            __builtin_amdgcn_global_load_lds((const AS1 u32*)srcB, (AS3 u32*)(smem + 16384 + L), 16, 0, 0);
        }
        __syncthreads();
#pragma unroll
        for (int kk = 0; kk < 2; ++kk) {
            i32x4 af[4], bfr[4];
#pragma unroll
            for (int m = 0; m < 4; ++m) {
                const int ra = wr * 64 + m * 16 + fr;
                af[m] = *(const i32x4*)(smem + ((ra << 7) | ((kk * 64 + fq * 16) ^ ((ra & 7) << 4))));
            }
#pragma unroll
            for (int n = 0; n < 4; ++n) {
                const int rb = wc * 64 + n * 16 + fr;
                bfr[n] = *(const i32x4*)(smem + 16384 + ((rb << 7) | ((kk * 64 + fq * 16) ^ ((rb & 7) << 4))));
            }
#pragma unroll
            for (int m = 0; m < 4; ++m)
#pragma unroll
                for (int n = 0; n < 4; ++n)
                    acc[m][n] = __builtin_amdgcn_mfma_i32_16x16x64_i8(af[m], bfr[n], acc[m][n], 0, 0, 0);
        }
    }

    float local = 0.f;
#pragma unroll
    for (int m = 0; m < 4; ++m) {
        const int rowb = r0 + wr * 64 + m * 16 + fq * 4;
#pragma unroll
        for (int n = 0; n < 4; ++n) {
            const int col = c0 + wc * 64 + n * 16 + fr;
#pragma unroll
            for (int r = 0; r < 4; ++r) {
                if (rowb + r != col) {
                    float s = fminf((float)acc[m][n][r] * QINV, 0.9999f);
                    local += -logf(1.0f - s + 1e-4f);
                }
            }
        }
    }
    if (bx > by) local *= 2.f;   // symmetric half counted twice

#pragma unroll
    for (int off = 32; off >= 1; off >>= 1) local += __shfl_xor(local, off, 64);
    if (lane == 0) red[wid] = local;
    __syncthreads();
    if (t == 0) partial[by * 32 + bx] = red[0] + red[1] + red[2] + red[3];
}

__global__ void k_reduce_geom(const float* __restrict__ partial, float* __restrict__ egeom)
{
    __shared__ float red[16];
    const int t = threadIdx.x;
    float v = partial[t];
#pragma unroll
    for (int off = 32; off >= 1; off >>= 1) v += __shfl_xor(v, off, 64);
    const int wave = t >> 6, lane = t & 63;
    if (lane == 0) red[wave] = v;
    __syncthreads();
    if (t == 0) {
        float s = 0.f;
        for (int i = 0; i < 16; ++i) s += red[i];
        egeom[0] = s / ((float)NR * (float)(NR - 1));
    }
}

// ============ top-64 by key -> exact fp32 recompute -> top-32 -> epilogue ====
__global__ __launch_bounds__(256) void k_finalize(
    const u32* __restrict__ cand, const u32* __restrict__ cnt,
    const float* __restrict__ x, const float* __restrict__ mu,
    const float* __restrict__ alpha, const float* __restrict__ kappa,
    const float* __restrict__ Ww, const float* __restrict__ Wb,
    const float* __restrict__ egeom, float* __restrict__ out)
{
    __shared__ u32   keys[4][CAP];
    __shared__ int   selid[4][TK];
    __shared__ float selex[4][TK];

    const int t = threadIdx.x, wave = t >> 6, lane = t & 63;
    const int row = blockIdx.x * 4 + wave;
    const int cn = (int)cnt[row];
    const int c = cn < CAP ? cn : CAP;

    for (int s = lane; s < c; s += 64)
        keys[wave][s] = cand[(size_t)row * CAP + s];
    __syncthreads();

    // iterative argmax: top-TK keys (value-major; distinct idx => no ties)
    for (int k = 0; k < TK; ++k) {
        u32 best = 0u; int bpos = -1;
        for (int s = lane; s < c; s += 64) {
            u32 v = keys[wave][s];
            if (v > best) { best = v; bpos = s; }
        }
#pragma unroll
        for (int off = 32; off >= 1; off >>= 1) {
            u32 v2 = __shfl_xor(best, off, 64);
            int p2 = __shfl_xor(bpos, off, 64);
            if (v2 > best) { best = v2; bpos = p2; }
        }
        if (lane == 0) {
            selid[wave][k] = (bpos >= 0) ? (int)(best & 0xFFFFu) : -1;
            if (bpos >= 0) keys[wave][bpos] = 0u;
        }
        __syncthreads();
    }

    // exact fp32 dots for the TK selected candidates (batched 4-wide)
    float xr[8];
    {
        const float4* xp = (const float4*)(x + (size_t)row * DD);
        float4 a = xp[lane * 2], b = xp[lane * 2 + 1];
        xr[0] = a.x; xr[1] = a.y; xr[2] = a.z; xr[3] = a.w;
        xr[4] = b.x; xr[5] = b.y; xr[6] = b.z; xr[7] = b.w;
    }
    for (int s0 = 0; s0 < TK; s0 += 4) {
        int idv[4];
        float4 a0[4], a1[4];
#pragma unroll
        for (int j = 0; j < 4; ++j) {
            idv[j] = selid[wave][s0 + j];              // wave-uniform
            const int rid = idv[j] >= 0 ? idv[j] : 0;
            const float4* mp = (const float4*)(mu + (size_t)rid * DD);
            a0[j] = mp[lane * 2];
            a1[j] = mp[lane * 2 + 1];
        }
        float d[4];
#pragma unroll
        for (int j = 0; j < 4; ++j)
            d[j] = xr[0] * a0[j].x + xr[1] * a0[j].y + xr[2] * a0[j].z + xr[3] * a0[j].w
                 + xr[4] * a1[j].x + xr[5] * a1[j].y + xr[6] * a1[j].z + xr[7] * a1[j].w;
#pragma unroll
        for (int j = 0; j < 4; ++j) {
#pragma unroll
            for (int off = 32; off >= 1; off >>= 1) d[j] += __shfl_xor(d[j], off, 64);
            if (lane == 0) selex[wave][s0 + j] = (idv[j] >= 0) ? d[j] : -INFINITY;
        }
    }
    __syncthreads();

    float v = selex[wave][lane];
    const int id = selid[wave][lane];
    bool alive = (id >= 0);

    // drop the 32 smallest exact values -> exact top-32 remains
    for (int rdrop = 0; rdrop < 32; ++rdrop) {
        float mn = alive ? v : INFINITY;
        int  mp2 = alive ? lane : 64;
#pragma unroll
        for (int off = 32; off >= 1; off >>= 1) {
            float m2 = __shfl_xor(mn, off, 64);
            int   p2 = __shfl_xor(mp2, off, 64);
            if (m2 < mn || (m2 == mn && p2 < mp2)) { mn = m2; mp2 = p2; }
        }
        if (lane == mp2) alive = false;
    }

    const float dv = alive ? v : -INFINITY;

    // top-1 / top-2 exact values (u, v of the reference)
    float m1 = dv; int p1 = alive ? lane : 64;
#pragma unroll
    for (int off = 32; off >= 1; off >>= 1) {
        float m2 = __shfl_xor(m1, off, 64);
        int   p2 = __shfl_xor(p1, off, 64);
        if (m2 > m1 || (m2 == m1 && p2 < p1)) { m1 = m2; p1 = p2; }
    }
    const float uu = m1;
    float s1 = (lane == p1) ? -INFINITY : dv;
#pragma unroll
    for (int off = 32; off >= 1; off >>= 1) s1 = fmaxf(s1, __shfl_xor(s1, off, 64));
    const float vv = s1;

    const int gid = alive ? id : 0;
    const float av = alpha[gid];
    const float kv = kappa[gid];
    float imp = alive ? fmaxf(kv, 1e-4f) : 0.f;
    float simp = imp;
#pragma unroll
    for (int off = 32; off >= 1; off >>= 1) simp += __shfl_xor(simp, off, 64);
    float w = fmaxf(imp / simp, 1e-8f);
    float tk = alive ? (av * (dv - 1.0f) * 10.0f + logf(w)) : -INFINITY;
    float mx = tk;
#pragma unroll
    for (int off = 32; off >= 1; off >>= 1) mx = fmaxf(mx, __shfl_xor(mx, off, 64));
    float se = alive ? expf(tk - mx) : 0.f;
#pragma unroll
    for (int off = 32; off >= 1; off >>= 1) se += __shfl_xor(se, off, 64);

    if (lane == 0) {
        float esplat = -(mx + logf(se));
        float z = Ww[0] * uu + Ww[1] * vv + Ww[2] * uu * vv + Wb[0];
        float ecomp = 1.f / (1.f + expf(-z));
        out[row] = esplat + 0.1f * egeom[0] + 0.1f * ecomp;
    }
}

extern "C" void kernel_launch(void* const* d_in, const int* in_sizes, int n_in,
                              void* d_out, int out_size, void* d_ws, size_t ws_size,
                              hipStream_t stream)
{
    const float* x     = (const float*)d_in[0];
    const float* mu    = (const float*)d_in[1];
    const float* alpha = (const float*)d_in[2];
    const float* kappa = (const float*)d_in[3];
    const float* Ww    = (const float*)d_in[4];
    const float* Wb    = (const float*)d_in[5];
    float* out = (float*)d_out;

    char* ws = (char*)d_ws;
    u32*   cnt     = (u32*)ws;
    float* partial = (float*)(ws + 16384);
    float* egeom   = (float*)(ws + 32768);
    char*  xi8     = (char*)(ws + 65536);
    char*  mui8    = (char*)(ws + 65536 + 2097152);
    u32*   cand    = (u32*)(ws + 65536 + 2097152 + 25600000);

    hipMemsetAsync(cnt, 0, NR * sizeof(u32), stream);

    k_quant<<<(NR * DD / 8 + 255) / 256, 256, 0, stream>>>(x, xi8, NR * DD / 8);
    k_quant<<<(MM * DD / 8 + 255) / 256, 256, 0, stream>>>(mu, mui8, MM * DD / 8);

    dim3 g1(NR / 128, (MM + 127) / 128);   // 32 x 391, row-panel fastest
    k_gemm_topk<<<g1, 256, 0, stream>>>(xi8, mui8, cnt, cand);

    dim3 g2(32, 32);
    k_geom<<<g2, 256, 0, stream>>>(xi8, partial);

    k_reduce_geom<<<1, 1024, 0, stream>>>(partial, egeom);

    k_finalize<<<NR / 4, 256, 0, stream>>>(cand, cnt, x, mu, alpha, kappa, Ww, Wb, egeom, out);
}

// Round 10
// 449.173 us; speedup vs baseline: 1.8054x; 1.3415x over previous
//
#include <hip/hip_runtime.h>
#include <math.h>

#define NR 4096
#define DD 512
#define MM 50000
#define CAP 640
#define TK 64
#define T0 0.118f
#define QS 400.0f
#define QINV (1.0f / 160000.0f)

typedef unsigned int u32;
typedef unsigned short u16;
typedef int i32x4 __attribute__((ext_vector_type(4)));

#define AS1 __attribute__((address_space(1)))
#define AS3 __attribute__((address_space(3)))

__device__ __forceinline__ u16 f2bf(float f) {
    u32 u = __float_as_uint(f);
    u32 r = (u + 0x7FFFu + ((u >> 16) & 1u)) >> 16;   // RNE
    return (u16)r;
}

// ---------------- ws layout ----------------
// [0,16384)                cnt (4096 u32)  -- zeroed each launch
// [16384,20480)            geom partials (1024 f32, fully written)
// [32768,32772)            e_geom scalar
// [65536, +2MB)            xi8  (4096x512 int8, scale 400)
// [+2MB, +27.6MB)          mui8 (50000x512 int8)
// [+27.6MB, +38.1MB)       cand keys (4096 x 640 u32 = {bf16val:16, idx:16})

// ============ int8 symmetric quantization (RNE, scale 400) ============
__global__ __launch_bounds__(256) void k_quant(const float* __restrict__ src,
                                               char* __restrict__ dst, int n8) {
    int i = blockIdx.x * 256 + threadIdx.x;
    if (i >= n8) return;
    const float4* s4 = (const float4*)src;
    float4 a = s4[(size_t)i * 2], b = s4[(size_t)i * 2 + 1];
    float v[8] = {a.x, a.y, a.z, a.w, b.x, b.y, b.z, b.w};
    u32 lo = 0, hi = 0;
#pragma unroll
    for (int j = 0; j < 4; ++j) {
        int q = __float2int_rn(v[j] * QS);
        q = q > 127 ? 127 : (q < -127 ? -127 : q);
        lo |= ((u32)(unsigned char)(char)q) << (8 * j);
    }
#pragma unroll
    for (int j = 0; j < 4; ++j) {
        int q = __float2int_rn(v[4 + j] * QS);
        q = q > 127 ? 127 : (q < -127 ? -127 : q);
        hi |= ((u32)(unsigned char)(char)q) << (8 * j);
    }
    *(uint2*)(dst + (size_t)i * 8) = make_uint2(lo, hi);
}

// ============ i8 MFMA GEMM x @ mu^T, 128x128 tile, threshold push ============
// R9 structure (BK=128, 128-B LDS rows, zero-conflict swizzle, single 32 KB
// buffer) + bijective XCD-aware remap: round-robin d%8 -> XCD, so give XCD x
// the contiguous (j,r) range p = x*1564 + d/8, r-fastest. Each mu col-panel
// is then consumed by ONE XCD (32 consecutive blocks) -> L2-hit staging.
__global__ __launch_bounds__(256, 5) void k_gemm_topk(
    const char* __restrict__ xi8, const char* __restrict__ mui8,
    u32* __restrict__ cnt, u32* __restrict__ cand)
{
    __shared__ char smem[32768];          // A 16KB | B 16KB

    const int t = threadIdx.x;
    const int lane = t & 63;
    const int wid = t >> 6;
    const int wr = wid >> 1, wc = wid & 1;
    const int fr = lane & 15, fq = lane >> 4;

    // ---- XCD-aware bijective remap (12512 blocks = 8 x 1564) ----
    const u32 d   = (u32)blockIdx.y * (u32)gridDim.x + (u32)blockIdx.x;
    const u32 xcd = d & 7u;
    const u32 p   = xcd * 1564u + (d >> 3);
    const int r0  = (int)(p & 31u) * 128;     // row-panel (fastest within XCD)
    const int c0  = (int)(p >> 5) * 128;      // col-panel (owned by one XCD)

    i32x4 acc[4][4];
#pragma unroll
    for (int m = 0; m < 4; ++m)
#pragma unroll
        for (int n = 0; n < 4; ++n) acc[m][n] = (i32x4){0, 0, 0, 0};

    for (int kt = 0; kt < DD; kt += 128) {
        __syncthreads();                  // previous tile fully consumed
#pragma unroll
        for (int i = 0; i < 4; ++i) {
            const int L  = i * 4096 + t * 16;
            const int rw = L >> 7;                 // 0..127 (128-B rows)
            const int cb = (L & 127) ^ ((rw & 7) << 4);
            const char* srcA = xi8 + (size_t)(r0 + rw) * DD + kt + cb;
            __builtin_amdgcn_global_load_lds((const AS1 u32*)srcA, (AS3 u32*)(smem + L), 16, 0, 0);
            int gr = c0 + rw; if (gr > MM - 1) gr = MM - 1;   // clamp, filtered at push
            const char* srcB = mui8 + (size_t)gr * DD + kt + cb;
            __builtin_amdgcn_global_load_lds((const AS1 u32*)srcB, (AS3 u32*)(smem + 16384 + L), 16, 0, 0);
        }
        __syncthreads();                  // staged tile visible (vmcnt drained)
#pragma unroll
        for (int kk = 0; kk < 2; ++kk) {  // two K=64 halves of BK=128
            i32x4 af[4], bfr[4];
#pragma unroll
            for (int m = 0; m < 4; ++m) {
                const int ra = wr * 64 + m * 16 + fr;
                af[m] = *(const i32x4*)(smem + ((ra << 7) | ((kk * 64 + fq * 16) ^ ((ra & 7) << 4))));
            }
#pragma unroll
            for (int n = 0; n < 4; ++n) {
                const int rb = wc * 64 + n * 16 + fr;
                bfr[n] = *(const i32x4*)(smem + 16384 + ((rb << 7) | ((kk * 64 + fq * 16) ^ ((rb & 7) << 4))));
            }
#pragma unroll
            for (int m = 0; m < 4; ++m)
#pragma unroll
                for (int n = 0; n < 4; ++n)
                    acc[m][n] = __builtin_amdgcn_mfma_i32_16x16x64_i8(af[m], bfr[n], acc[m][n], 0, 0, 0);
        }
    }

    // C/D layout (m89): col = lane&15, row = (lane>>4)*4 + reg
#pragma unroll
    for (int m = 0; m < 4; ++m) {
        const int rowb = r0 + wr * 64 + m * 16 + fq * 4;
#pragma unroll
        for (int n = 0; n < 4; ++n) {
            const int col = c0 + wc * 64 + n * 16 + fr;
#pragma unroll
            for (int r = 0; r < 4; ++r) {
                const float v = (float)acc[m][n][r] * QINV;
                if (v >= T0 && col < MM) {
                    u32 pos = atomicAdd(&cnt[rowb + r], 1u);
                    if (pos < CAP)
                        cand[(size_t)(rowb + r) * CAP + pos] =
                            (((u32)f2bf(v)) << 16) | (u32)col;
                }
            }
        }
    }
}

// ============ x @ x^T geometric energy (same structure, triangular) ========
__global__ __launch_bounds__(256, 5) void k_geom(
    const char* __restrict__ xi8, float* __restrict__ partial)
{
    const int bx = blockIdx.x, by = blockIdx.y;
    const int t = threadIdx.x;
    if (bx < by) { if (t == 0) partial[by * 32 + bx] = 0.f; return; }

    __shared__ char smem[32768];
    __shared__ float red[4];

    const int lane = t & 63;
    const int wid = t >> 6;
    const int wr = wid >> 1, wc = wid & 1;
    const int fr = lane & 15, fq = lane >> 4;
    const int r0 = by * 128;
    const int c0 = bx * 128;

    i32x4 acc[4][4];
#pragma unroll
    for (int m = 0; m < 4; ++m)
#pragma unroll
        for (int n = 0; n < 4; ++n) acc[m][n] = (i32x4){0, 0, 0, 0};

    for (int kt = 0; kt < DD; kt += 128) {
        __syncthreads();
#pragma unroll
        for (int i = 0; i < 4; ++i) {
            const int L  = i * 4096 + t * 16;
            const int rw = L >> 7;
            const int cb = (L & 127) ^ ((rw & 7) << 4);
            const char* srcA = xi8 + (size_t)(r0 + rw) * DD + kt + cb;
            __builtin_amdgcn_global_load_lds((const AS1 u32*)srcA, (AS3 u32*)(smem + L), 16, 0, 0);
            const char* srcB = xi8 + (size_t)(c0 + rw) * DD + kt + cb;
            __builtin_amdgcn_global_load_lds((const AS1 u32*)srcB, (AS3 u32*)(smem + 16384 + L), 16, 0, 0);
        }
        __syncthreads();
#pragma unroll
        for (int kk = 0; kk < 2; ++kk) {
            i32x4 af[4], bfr[4];
#pragma unroll
            for (int m = 0; m < 4; ++m) {
                const int ra = wr * 64 + m * 16 + fr;
                af[m] = *(const i32x4*)(smem + ((ra << 7) | ((kk * 64 + fq * 16) ^ ((ra & 7) << 4))));
            }
#pragma unroll
            for (int n = 0; n < 4; ++n) {
                const int rb = wc * 64 + n * 16 + fr;
                bfr[n] = *(const i32x4*)(smem + 16384 + ((rb << 7) | ((kk * 64 + fq * 16) ^ ((rb & 7) << 4))));
            }
#pragma unroll
            for (int m = 0; m < 4; ++m)
#pragma unroll
                for (int n = 0; n < 4; ++n)
                    acc[m][n] = __builtin_amdgcn_mfma_i32_16x16x64_i8(af[m], bfr[n], acc[m][n], 0, 0, 0);
        }
    }

    float local = 0.f;
#pragma unroll
    for (int m = 0; m < 4; ++m) {
        const int rowb = r0 + wr * 64 + m * 16 + fq * 4;
#pragma unroll
        for (int n = 0; n < 4; ++n) {
            const int col = c0 + wc * 64 + n * 16 + fr;
#pragma unroll
            for (int r = 0; r < 4; ++r) {
                if (rowb + r != col) {
                    float s = fminf((float)acc[m][n][r] * QINV, 0.9999f);
                    local += -logf(1.0f - s + 1e-4f);
                }
            }
        }
    }
    if (bx > by) local *= 2.f;   // symmetric half counted twice

#pragma unroll
    for (int off = 32; off >= 1; off >>= 1) local += __shfl_xor(local, off, 64);
    if (lane == 0) red[wid] = local;
    __syncthreads();
    if (t == 0) partial[by * 32 + bx] = red[0] + red[1] + red[2] + red[3];
}

__global__ void k_reduce_geom(const float* __restrict__ partial, float* __restrict__ egeom)
{
    __shared__ float red[16];
    const int t = threadIdx.x;
    float v = partial[t];
#pragma unroll
    for (int off = 32; off >= 1; off >>= 1) v += __shfl_xor(v, off, 64);
    const int wave = t >> 6, lane = t & 63;
    if (lane == 0) red[wave] = v;
    __syncthreads();
    if (t == 0) {
        float s = 0.f;
        for (int i = 0; i < 16; ++i) s += red[i];
        egeom[0] = s / ((float)NR * (float)(NR - 1));
    }
}

// ===== finalize: 1 wave per row. top-64 by key -> exact fp32 -> epilogue =====
__global__ __launch_bounds__(64) void k_finalize(
    const u32* __restrict__ cand, const u32* __restrict__ cnt,
    const float* __restrict__ x, const float* __restrict__ mu,
    const float* __restrict__ alpha, const float* __restrict__ kappa,
    const float* __restrict__ Ww, const float* __restrict__ Wb,
    const float* __restrict__ egeom, float* __restrict__ out)
{
    __shared__ u32   keys[CAP];
    __shared__ int   selid[TK];
    __shared__ float selex[TK];

    const int lane = threadIdx.x;
    const int row = blockIdx.x;
    const int cn = (int)cnt[row];
    const int c = cn < CAP ? cn : CAP;

    for (int s = lane; s < c; s += 64)
        keys[s] = cand[(size_t)row * CAP + s];
    __syncthreads();

    // iterative argmax: top-TK keys (value-major; distinct idx => no ties)
    for (int k = 0; k < TK; ++k) {
        u32 best = 0u; int bpos = -1;
        for (int s = lane; s < c; s += 64) {
            u32 v = keys[s];
            if (v > best) { best = v; bpos = s; }
        }
#pragma unroll
        for (int off = 32; off >= 1; off >>= 1) {
            u32 v2 = __shfl_xor(best, off, 64);
            int p2 = __shfl_xor(bpos, off, 64);
            if (v2 > best) { best = v2; bpos = p2; }
        }
        if (lane == 0) {
            selid[k] = (bpos >= 0) ? (int)(best & 0xFFFFu) : -1;
            if (bpos >= 0) keys[bpos] = 0u;
        }
        __syncthreads();
    }

    // exact fp32 dots for the TK selected candidates (batched 4-wide)
    float xr[8];
    {
        const float4* xp = (const float4*)(x + (size_t)row * DD);
        float4 a = xp[lane * 2], b = xp[lane * 2 + 1];
        xr[0] = a.x; xr[1] = a.y; xr[2] = a.z; xr[3] = a.w;
        xr[4] = b.x; xr[5] = b.y; xr[6] = b.z; xr[7] = b.w;
    }
    for (int s0 = 0; s0 < TK; s0 += 4) {
        int idv[4];
        float4 a0[4], a1[4];
#pragma unroll
        for (int j = 0; j < 4; ++j) {
            idv[j] = selid[s0 + j];                    // wave-uniform
            const int rid = idv[j] >= 0 ? idv[j] : 0;
            const float4* mp = (const float4*)(mu + (size_t)rid * DD);
            a0[j] = mp[lane * 2];
            a1[j] = mp[lane * 2 + 1];
        }
        float d[4];
#pragma unroll
        for (int j = 0; j < 4; ++j)
            d[j] = xr[0] * a0[j].x + xr[1] * a0[j].y + xr[2] * a0[j].z + xr[3] * a0[j].w
                 + xr[4] * a1[j].x + xr[5] * a1[j].y + xr[6] * a1[j].z + xr[7] * a1[j].w;
#pragma unroll
        for (int j = 0; j < 4; ++j) {
#pragma unroll
            for (int off = 32; off >= 1; off >>= 1) d[j] += __shfl_xor(d[j], off, 64);
            if (lane == 0) selex[s0 + j] = (idv[j] >= 0) ? d[j] : -INFINITY;
        }
    }
    __syncthreads();

    float v = selex[lane];
    const int id = selid[lane];
    bool alive = (id >= 0);

    // drop the 32 smallest exact values -> exact top-32 remains
    for (int rdrop = 0; rdrop < 32; ++rdrop) {
        float mn = alive ? v : INFINITY;
        int  mp2 = alive ? lane : 64;
#pragma unroll
        for (int off = 32; off >= 1; off >>= 1) {
            float m2 = __shfl_xor(mn, off, 64);
            int   p2 = __shfl_xor(mp2, off, 64);
            if (m2 < mn || (m2 == mn && p2 < mp2)) { mn = m2; mp2 = p2; }
        }
        if (lane == mp2) alive = false;
    }

    const float dv = alive ? v : -INFINITY;

    // top-1 / top-2 exact values (u, v of the reference)
    float m1 = dv; int p1 = alive ? lane : 64;
#pragma unroll
    for (int off = 32; off >= 1; off >>= 1) {
        float m2 = __shfl_xor(m1, off, 64);
        int   p2 = __shfl_xor(p1, off, 64);
        if (m2 > m1 || (m2 == m1 && p2 < p1)) { m1 = m2; p1 = p2; }
    }
    const float uu = m1;
    float s1 = (lane == p1) ? -INFINITY : dv;
#pragma unroll
    for (int off = 32; off >= 1; off >>= 1) s1 = fmaxf(s1, __shfl_xor(s1, off, 64));
    const float vv = s1;

    const int gid = alive ? id : 0;
    const float av = alpha[gid];
    const float kv = kappa[gid];
    float imp = alive ? fmaxf(kv, 1e-4f) : 0.f;
    float simp = imp;
#pragma unroll
    for (int off = 32; off >= 1; off >>= 1) simp += __shfl_xor(simp, off, 64);
    float w = fmaxf(imp / simp, 1e-8f);
    float tk = alive ? (av * (dv - 1.0f) * 10.0f + logf(w)) : -INFINITY;
    float mx = tk;
#pragma unroll
    for (int off = 32; off >= 1; off >>= 1) mx = fmaxf(mx, __shfl_xor(mx, off, 64));
    float se = alive ? expf(tk - mx) : 0.f;
#pragma unroll
    for (int off = 32; off >= 1; off >>= 1) se += __shfl_xor(se, off, 64);

    if (lane == 0) {
        float esplat = -(mx + logf(se));
        float z = Ww[0] * uu + Ww[1] * vv + Ww[2] * uu * vv + Wb[0];
        float ecomp = 1.f / (1.f + expf(-z));
        out[row] = esplat + 0.1f * egeom[0] + 0.1f * ecomp;
    }
}

extern "C" void kernel_launch(void* const* d_in, const int* in_sizes, int n_in,
                              void* d_out, int out_size, void* d_ws, size_t ws_size,
                              hipStream_t stream)
{
    const float* x     = (const float*)d_in[0];
    const float* mu    = (const float*)d_in[1];
    const float* alpha = (const float*)d_in[2];
    const float* kappa = (const float*)d_in[3];
    const float* Ww    = (const float*)d_in[4];
    const float* Wb    = (const float*)d_in[5];
    float* out = (float*)d_out;

    char* ws = (char*)d_ws;
    u32*   cnt     = (u32*)ws;
    float* partial = (float*)(ws + 16384);
    float* egeom   = (float*)(ws + 32768);
    char*  xi8     = (char*)(ws + 65536);
    char*  mui8    = (char*)(ws + 65536 + 2097152);
    u32*   cand    = (u32*)(ws + 65536 + 2097152 + 25600000);

    hipMemsetAsync(cnt, 0, NR * sizeof(u32), stream);

    k_quant<<<(NR * DD / 8 + 255) / 256, 256, 0, stream>>>(x, xi8, NR * DD / 8);
    k_quant<<<(MM * DD / 8 + 255) / 256, 256, 0, stream>>>(mu, mui8, MM * DD / 8);

    dim3 g1(NR / 128, (MM + 127) / 128);   // 32 x 391 = 12512 = 8 x 1564
    k_gemm_topk<<<g1, 256, 0, stream>>>(xi8, mui8, cnt, cand);

    dim3 g2(32, 32);
    k_geom<<<g2, 256, 0, stream>>>(xi8, partial);

    k_reduce_geom<<<1, 1024, 0, stream>>>(partial, egeom);

    k_finalize<<<NR, 64, 0, stream>>>(cand, cnt, x, mu, alpha, kappa, Ww, Wb, egeom, out);
}